// Round 3
// baseline (534.919 us; speedup 1.0000x reference)
//
#include <hip/hip_runtime.h>
#include <stdint.h>
#include <stddef.h>

typedef __bf16 bf16;
typedef __bf16 bf16x8 __attribute__((ext_vector_type(8)));
typedef float  f32x4  __attribute__((ext_vector_type(4)));

#define GLOBAL_AS(p) ((const __attribute__((address_space(1))) void*)(p))
#define LDS_AS(p)    ((__attribute__((address_space(3))) void*)(p))

__device__ __forceinline__ void gload_lds16(const bf16* g, bf16* l) {
    // global_load_lds_dwordx4: LDS dest = wave-uniform base + lane*16 (caller guarantees)
    __builtin_amdgcn_global_load_lds(GLOBAL_AS(g), LDS_AS(l), 16, 0, 0);
}

// ---------------------------------------------------------------------------
// x (f32) -> bf16, 8 elems/thread, both directions coalesced
// ---------------------------------------------------------------------------
__global__ __launch_bounds__(256)
void convert_x_kernel(const float* __restrict__ x, bf16* __restrict__ xb, long n8) {
    long t = (long)blockIdx.x * blockDim.x + threadIdx.x;
    if (t >= n8) return;
    const f32x4* p = (const f32x4*)(x + t * 8);
    f32x4 a = p[0], b = p[1];
    bf16x8 v;
#pragma unroll
    for (int j = 0; j < 4; ++j) { v[j] = (bf16)a[j]; v[4 + j] = (bf16)b[j]; }
    *(bf16x8*)(xb + t * 8) = v;
}

// ---------------------------------------------------------------------------
// Dequant to K-TILED layout for BK=64: Wt[K/64][N][64], Wt[t][o][cc] = W^T[o][t*64+cc]
// ---------------------------------------------------------------------------
__global__ __launch_bounds__(256)
void dequant_wt64_kernel(const uint32_t* __restrict__ qw,
                         const float* __restrict__ scales,
                         const float* __restrict__ qzeros,
                         bf16* __restrict__ Wt,
                         int N, int K, int rows_per_group) {
    const int i = blockIdx.x * 256 + threadIdx.x;
    const int w = i >> 6, l = i & 63;
    const int nr8 = K >> 6;                  // 8-row groups (64 k each)
    const int r8 = w % nr8;
    const int o  = (w / nr8) * 8 + (l >> 3);
    const int rr = l & 7;
    const int r  = r8 * 8 + rr;              // qweight row; k = r*8 + j
    if (o >= N) return;
    const uint32_t q = qw[(size_t)r * N + o];
    const int g = r / rows_per_group;
    const float s = scales[(size_t)g * N + o];
    const float z = qzeros[(size_t)g * N + o];
    const float nsz = -s * z;
    bf16x8 v;
#pragma unroll
    for (int j = 0; j < 8; ++j)
        v[j] = (bf16)fmaf((float)((q >> (4 * j)) & 15u), s, nsz);
    *(bf16x8*)(Wt + ((size_t)r8 * N + o) * 64 + rr * 8) = v;
}

// ===========================================================================
// 256x256 8-phase GEMM — SCHEDULE F (front-loaded reads, 3-phase prefetch).
//   8 waves (2M x 4N), BK=64, LDS = 2 bufs x (A 32KB + B 32KB) = 128KB.
//   Per wave: 128x64 C = acc[8][4] f32x4.  16 MFMA per phase.
//
// Iteration i reads tile T=2i from buf0 (ph1-4) and T+1 from buf1 (ph5-8).
//   ph1: read buf0 kk0 a0[8]+b0[4]; stage (T+1).B0,B1 -> buf1 ; MFMA kk0 i0-3
//   ph2: read buf0 kk1 a1[8]+b1[4];                             MFMA kk0 i4-7
//        (lgkm drain moved AFTER the MFMA, before END barrier)
//   ph3: stage (T+2).A0 -> buf0 ;                               MFMA kk1 i0-3
//   ph4: stage (T+2).A1 -> buf0 ;                               MFMA kk1 i4-7 ; vmcnt(4)
//   ph5: read buf1 kk0; stage (T+2).B0,B1 -> buf0 ;             MFMA kk0 i0-3
//   ph6: read buf1 kk1;                                         MFMA kk0 i4-7 (END_LG)
//   ph7: stage (T+3).A0 -> buf1 ;                               MFMA kk1 i0-3
//   ph8: stage (T+3).A1 -> buf1 ;                               MFMA kk1 i4-7 ; vmcnt(4)
//
// vmcnt accounting (2 global_load_lds per half-stage; B-stage = 2 halves = 4):
//   entry outstanding = 4 (A(T+1) from prev ph7/ph8)
//   ph1 +4 -> 8; ph3 +2 -> 10; ph4 +2 -> 12; vmcnt(4) drains A(T+1)+B(T+1)
//     => tile T+1 fully landed before ph5 reads; leaves A(T+2)=4.
//   ph5 +4 -> 8; ph7 +2 -> 10; ph8 +2 -> 12; vmcnt(4) drains A(T+2)+B(T+2)
//     => buf0 tile T+2 landed before next ph1; leaves A(T+3)=4 (invariant).
// Stage->wait distances: B pairs = 3 phases, A halves = 5 phases (was 2).
//
// WAR audit (stage must follow the barrier AFTER all reads of that region
// retired; reads retire at the lgkm(0) of their own phase, incl. the END_LG
// drains at ph2/ph6 which complete before the ph2/ph6 END barrier):
//   buf1.B staged ph1 : old reads prev-ph5/ph6, retired by prev-ph6 END. OK
//   buf0.A staged ph3/4: reads ph1(a0)+ph2(a1) retired by ph2 END (END_LG). OK
//   buf0.B staged ph5 : reads ph1(b0)+ph2(b1) retired by ph2 END. OK
//   buf1.A staged ph7/8: reads ph5(a0)+ph6(a1) retired by ph6 END (END_LG). OK
// Tail: clamped dummy stages keep vmcnt counts exact; dummy targets are only
// written after their final reads (same windows), never re-read.
//
// Deadlock audit (R2 container failure was infra; re-verified): no divergent
// barriers (uniform control flow, no early return), vmcnt waits always
// satisfiable, LDS offsets < 32KB per buffer, gload dest = uniform base +
// lane*16 exactly.
//
// LDS swizzle (both-sides, rule #21) unchanged from R1 (bank conflicts = 0).
// ===========================================================================
constexpr int BM2 = 256, BN2 = 256, BK2 = 64;

#define PHASE_MID()                                      \
    __builtin_amdgcn_s_barrier();                        \
    asm volatile("s_waitcnt lgkmcnt(0)" ::: "memory");   \
    __builtin_amdgcn_sched_barrier(0);                   \
    __builtin_amdgcn_s_setprio(1)

// no-lgkm MID: used when this phase's MFMA does not consume this phase's reads
#define PHASE_MID_NOLG()                                 \
    __builtin_amdgcn_s_barrier();                        \
    __builtin_amdgcn_sched_barrier(0);                   \
    __builtin_amdgcn_s_setprio(1)

#define PHASE_END()                                      \
    __builtin_amdgcn_s_setprio(0);                       \
    __builtin_amdgcn_sched_barrier(0);                   \
    __builtin_amdgcn_s_barrier();                        \
    __builtin_amdgcn_sched_barrier(0)

// END with lgkm drain (pairs with PHASE_MID_NOLG): this phase's reads retire
// under the MFMA, but are guaranteed complete before the END barrier, so the
// next phase may stage over the region they read.
#define PHASE_END_LG()                                   \
    __builtin_amdgcn_s_setprio(0);                       \
    __builtin_amdgcn_sched_barrier(0);                   \
    asm volatile("s_waitcnt lgkmcnt(0)" ::: "memory");   \
    __builtin_amdgcn_s_barrier();                        \
    __builtin_amdgcn_sched_barrier(0)

#define PHASE_END_VM4()                                  \
    __builtin_amdgcn_s_setprio(0);                       \
    __builtin_amdgcn_sched_barrier(0);                   \
    asm volatile("s_waitcnt vmcnt(4)" ::: "memory");     \
    __builtin_amdgcn_s_barrier();                        \
    __builtin_amdgcn_sched_barrier(0)

#define MFMA_HALF(A, B, IBASE)                                             \
    _Pragma("unroll")                                                      \
    for (int i_ = 0; i_ < 4; ++i_) {                                       \
        _Pragma("unroll")                                                  \
        for (int j_ = 0; j_ < 4; ++j_)                                     \
            acc[(IBASE) + i_][j_] = __builtin_amdgcn_mfma_f32_16x16x32_bf16( \
                (A)[(IBASE) + i_], (B)[j_], acc[(IBASE) + i_][j_], 0, 0, 0); \
    }

__global__ __launch_bounds__(512, 2)
void gemm8_kernel(const bf16* __restrict__ Ab,   // [M][K] bf16
                  const bf16* __restrict__ Bt,   // [K/64][N][64] bf16 (= W^T k-tiled)
                  const float* __restrict__ bias,
                  float* __restrict__ out,
                  int M, int N, int K, int nbx) {
    __shared__ __align__(16) bf16 As[2][BM2 * BK2];   // 2 x 32KB
    __shared__ __align__(16) bf16 Bs[2][BN2 * BK2];   // 2 x 32KB

    const int tid  = threadIdx.x;
    const int lane = tid & 63;
    const int wave = tid >> 6;
    const int wm = wave >> 2;        // 0..1
    const int wn = wave & 3;         // 0..3

    // T1: bijective XCD swizzle (m204), column-fast so the ~32 concurrent
    // blocks on one XCD share a single 2MB B-panel (fits 4MB XCD L2).
    const int nwg = gridDim.x;
    int wg = blockIdx.x;
    {
        const int q = nwg >> 3, r = nwg & 7;
        const int xcd = wg & 7, off = wg >> 3;
        wg = (xcd < r ? xcd * (q + 1) : r * (q + 1) + (xcd - r) * q) + off;
    }
    const int nby = nwg / nbx;
    const int bx = wg / nby;
    const int by = wg % nby;
    const int m0 = by * BM2;
    const int n0 = bx * BN2;

    const int lrow = lane & 15;
    const int lhi  = lane >> 4;
    const int swz  = (lrow >> 1) & 7;

    const int NT = K >> 6;           // K-tiles
    const int NI = NT >> 1;          // iterations (2 tiles each); K%128==0 guaranteed

    auto stageA = [&](int tIdx, int half, int buf) {
#pragma unroll
        for (int it = 0; it < 2; ++it) {
            const int q  = tid + it * 512;          // chunk in half-tile [0,1024)
            const int rl = q >> 3;                  // row within half
            const int cl = (q & 7) ^ ((rl >> 1) & 7);  // inverse-swizzled source chunk
            gload_lds16(Ab + (size_t)(m0 + half * 128 + rl) * K + tIdx * 64 + cl * 8,
                        &As[buf][half * 8192 + q * 8]);   // linear LDS dest
        }
    };
    auto stageB = [&](int tIdx, int half, int buf) {
#pragma unroll
        for (int it = 0; it < 2; ++it) {
            const int q  = tid + it * 512;
            const int rl = q >> 3;
            const int cl = (q & 7) ^ ((rl >> 1) & 7);
            gload_lds16(Bt + ((size_t)tIdx * N + n0 + half * 128 + rl) * 64 + cl * 8,
                        &Bs[buf][half * 8192 + q * 8]);
        }
    };

    f32x4 acc[8][4];
#pragma unroll
    for (int i = 0; i < 8; ++i)
#pragma unroll
        for (int j = 0; j < 4; ++j) acc[i][j] = (f32x4){0.f, 0.f, 0.f, 0.f};

    // prologue: tile0 complete (buf0) + tile1 A-halves (buf1) in flight
    stageA(0, 0, 0); stageA(0, 1, 0); stageB(0, 0, 0); stageB(0, 1, 0);
    stageA(1, 0, 1); stageA(1, 1, 1);
    asm volatile("s_waitcnt vmcnt(4)" ::: "memory");   // tile0's 8 loads landed
    __builtin_amdgcn_s_barrier();
    __builtin_amdgcn_sched_barrier(0);

    bf16x8 a0[8], a1[8], b0[4], b1[4];

    for (int i2 = 0; i2 < NI; ++i2) {
        const int t0  = 2 * i2;
        const int tB1 = t0 + 1;                           // buf1 tile (< NT always)
        const int tS2 = (t0 + 2 < NT) ? t0 + 2 : NT - 1;  // clamped dummy at tail
        const int tS3 = (t0 + 3 < NT) ? t0 + 3 : NT - 1;

        // ---- phase 1: read buf0 kk0; stage (T+1).B pair -> buf1; mfma kk0 i0-3
#pragma unroll
        for (int i = 0; i < 8; ++i)
            a0[i] = *(const bf16x8*)(&As[0][(wm * 128 + i * 16 + lrow) * 64 + ((lhi ^ swz) * 8)]);
#pragma unroll
        for (int j = 0; j < 4; ++j)
            b0[j] = *(const bf16x8*)(&Bs[0][(wn * 64 + j * 16 + lrow) * 64 + ((lhi ^ swz) * 8)]);
        stageB(tB1, 0, 1);
        stageB(tB1, 1, 1);
        PHASE_MID();
        MFMA_HALF(a0, b0, 0);
        PHASE_END();

        // ---- phase 2: read buf0 kk1; mfma kk0 i4-7 (reads retire under MFMA)
#pragma unroll
        for (int i = 0; i < 8; ++i)
            a1[i] = *(const bf16x8*)(&As[0][(wm * 128 + i * 16 + lrow) * 64 + (((lhi + 4) ^ swz) * 8)]);
#pragma unroll
        for (int j = 0; j < 4; ++j)
            b1[j] = *(const bf16x8*)(&Bs[0][(wn * 64 + j * 16 + lrow) * 64 + (((lhi + 4) ^ swz) * 8)]);
        PHASE_MID_NOLG();
        MFMA_HALF(a0, b0, 4);
        PHASE_END_LG();

        // ---- phase 3: stage (T+2).A0 -> buf0; mfma kk1 i0-3
        stageA(tS2, 0, 0);
        PHASE_MID();
        MFMA_HALF(a1, b1, 0);
        PHASE_END();

        // ---- phase 4: stage (T+2).A1 -> buf0; mfma kk1 i4-7; counted vmcnt
        stageA(tS2, 1, 0);
        PHASE_MID();
        MFMA_HALF(a1, b1, 4);
        PHASE_END_VM4();               // tile T+1 fully landed; A(T+2) in flight

        // ---- phase 5: read buf1 kk0; stage (T+2).B pair -> buf0; mfma kk0 i0-3
#pragma unroll
        for (int i = 0; i < 8; ++i)
            a0[i] = *(const bf16x8*)(&As[1][(wm * 128 + i * 16 + lrow) * 64 + ((lhi ^ swz) * 8)]);
#pragma unroll
        for (int j = 0; j < 4; ++j)
            b0[j] = *(const bf16x8*)(&Bs[1][(wn * 64 + j * 16 + lrow) * 64 + ((lhi ^ swz) * 8)]);
        stageB(tS2, 0, 0);
        stageB(tS2, 1, 0);
        PHASE_MID();
        MFMA_HALF(a0, b0, 0);
        PHASE_END();

        // ---- phase 6: read buf1 kk1; mfma kk0 i4-7 (reads retire under MFMA)
#pragma unroll
        for (int i = 0; i < 8; ++i)
            a1[i] = *(const bf16x8*)(&As[1][(wm * 128 + i * 16 + lrow) * 64 + (((lhi + 4) ^ swz) * 8)]);
#pragma unroll
        for (int j = 0; j < 4; ++j)
            b1[j] = *(const bf16x8*)(&Bs[1][(wn * 64 + j * 16 + lrow) * 64 + (((lhi + 4) ^ swz) * 8)]);
        PHASE_MID_NOLG();
        MFMA_HALF(a0, b0, 4);
        PHASE_END_LG();

        // ---- phase 7: stage (T+3).A0 -> buf1; mfma kk1 i0-3
        stageA(tS3, 0, 1);
        PHASE_MID();
        MFMA_HALF(a1, b1, 0);
        PHASE_END();

        // ---- phase 8: stage (T+3).A1 -> buf1; mfma kk1 i4-7; counted vmcnt
        stageA(tS3, 1, 1);
        PHASE_MID();
        MFMA_HALF(a1, b1, 4);
        PHASE_END_VM4();               // buf0 tile T+2 landed; A(T+3) in flight
    }

    asm volatile("s_waitcnt vmcnt(0)" ::: "memory");   // drain before LDS dealloc

    // epilogue: D layout col=lane&15 (n), row=(lane>>4)*4+reg (m); f32 out
#pragma unroll
    for (int j = 0; j < 4; ++j) {
        const int col = n0 + wn * 64 + j * 16 + lrow;
        const float bv = bias[col];
#pragma unroll
        for (int i = 0; i < 8; ++i) {
            const int rbase = m0 + wm * 128 + i * 16 + lhi * 4;
#pragma unroll
            for (int r = 0; r < 4; ++r)
                out[(size_t)(rbase + r) * N + col] = acc[i][j][r] + bv;
        }
    }
}

// ---------------------------------------------------------------------------
// FUSED fallback (small-ws only): f32 x + qweight dequant in-flight.
// 128x128 tile, BK=32, 4 waves (2x2), 4x4 of mfma_f32_16x16x32_bf16.
// ---------------------------------------------------------------------------
constexpr int BM = 128, BN = 128, BK = 32;

__global__ __launch_bounds__(256)
void gemm_fused_kernel(const float* __restrict__ Af,      // [M,K] f32
                       const uint32_t* __restrict__ qw,   // [K/8,N]
                       const float* __restrict__ scales,  // [K/G,N] f32
                       const float* __restrict__ qzeros,  // [K/G,N] f32
                       const float* __restrict__ bias,    // [N] f32
                       float* __restrict__ out,           // [M,N] f32
                       int M, int N, int K, int G) {
    __shared__ __align__(16) bf16 As2[BM * BK];
    __shared__ __align__(16) bf16 Bs2[BN * BK];

    const int tid  = threadIdx.x;
    const int lane = tid & 63;
    const int wave = tid >> 6;
    const int wmm = wave & 1;
    const int wnn = wave >> 1;
    const int m0 = blockIdx.y * BM;
    const int n0 = blockIdx.x * BN;

    const int lr = lane & 15;
    const int lk8 = (lane >> 4) * 8;

    f32x4 acc[4][4];
#pragma unroll
    for (int i = 0; i < 4; ++i)
#pragma unroll
        for (int j = 0; j < 4; ++j) acc[i][j] = (f32x4){0.f, 0.f, 0.f, 0.f};

    for (int kt = 0; kt < K; kt += BK) {
#pragma unroll
        for (int it = 0; it < 2; ++it) {
            const int c = tid + it * 256;
            const int row = c >> 2;
            const int kc  = (c & 3) * 8;
            const f32x4* p = (const f32x4*)(Af + (size_t)(m0 + row) * K + kt + kc);
            f32x4 a = p[0], b = p[1];
            bf16x8 v;
#pragma unroll
            for (int j = 0; j < 4; ++j) { v[j] = (bf16)a[j]; v[4 + j] = (bf16)b[j]; }
            *(bf16x8*)(As2 + row * BK + kc) = v;
        }
        const int g = kt / G;
#pragma unroll
        for (int it = 0; it < 2; ++it) {
            const int idx = tid + it * 256;
            const int rl = idx >> 7;
            const int nl = idx & 127;
            uint32_t q = qw[(size_t)(kt / 8 + rl) * N + n0 + nl];
            float s = scales[(size_t)g * N + n0 + nl];
            float z = qzeros[(size_t)g * N + n0 + nl];
            float nsz = -s * z;
            bf16x8 v;
#pragma unroll
            for (int j = 0; j < 8; ++j)
                v[j] = (bf16)fmaf((float)((q >> (4 * j)) & 15u), s, nsz);
            *(bf16x8*)(Bs2 + nl * BK + rl * 8) = v;
        }
        __syncthreads();

        bf16x8 a[4], b[4];
#pragma unroll
        for (int i = 0; i < 4; ++i)
            a[i] = *(const bf16x8*)(As2 + (wmm * 64 + i * 16 + lr) * BK + lk8);
#pragma unroll
        for (int j = 0; j < 4; ++j)
            b[j] = *(const bf16x8*)(Bs2 + (wnn * 64 + j * 16 + lr) * BK + lk8);

#pragma unroll
        for (int i = 0; i < 4; ++i)
#pragma unroll
            for (int j = 0; j < 4; ++j)
                acc[i][j] = __builtin_amdgcn_mfma_f32_16x16x32_bf16(
                    a[i], b[j], acc[i][j], 0, 0, 0);
        __syncthreads();
    }

#pragma unroll
    for (int j = 0; j < 4; ++j) {
        const int col = n0 + wnn * 64 + j * 16 + (lane & 15);
        const float bv = bias[col];
#pragma unroll
        for (int i = 0; i < 4; ++i) {
            const int rbase = m0 + wmm * 64 + i * 16 + (lane >> 4) * 4;
#pragma unroll
            for (int r = 0; r < 4; ++r)
                out[(size_t)(rbase + r) * N + col] = acc[i][j][r] + bv;
        }
    }
}

extern "C" void kernel_launch(void* const* d_in, const int* in_sizes, int n_in,
                              void* d_out, int out_size, void* d_ws, size_t ws_size,
                              hipStream_t stream) {
    // fp16 reference tensors are stored as FLOAT32 by the harness
    const float*    x      = (const float*)d_in[0];
    const uint32_t* qw     = (const uint32_t*)d_in[1];
    const float*    scales = (const float*)d_in[2];
    const float*    qzeros = (const float*)d_in[3];
    const float*    bias   = (const float*)d_in[4];
    float*          out    = (float*)d_out;

    const int N = in_sizes[4];                 // 4096
    const int K = (in_sizes[1] / N) * 8;       // 4096
    const int M = in_sizes[0] / K;             // 8192
    const int G = K / (in_sizes[2] / N);       // 64

    const size_t xb_bytes = (size_t)M * K * sizeof(bf16);   // 64 MB
    const size_t wt_bytes = (size_t)N * K * sizeof(bf16);   // 32 MB

    const bool shape_ok = (M % BM2 == 0) && (N % BN2 == 0) && (K % 128 == 0) &&
                          (G % 8 == 0);

    if (shape_ok && ws_size >= xb_bytes + wt_bytes) {
        bf16* Xb = (bf16*)d_ws;
        bf16* Wt = (bf16*)((char*)d_ws + xb_bytes);
        const long n8 = (long)M * K / 8;
        convert_x_kernel<<<(int)((n8 + 255) / 256), 256, 0, stream>>>(x, Xb, n8);
        // waves = (K/64) * (N/8); threads = waves*64
        const long dq_threads = ((long)K >> 6) * (N / 8) * 64;
        dequant_wt64_kernel<<<(int)((dq_threads + 255) / 256), 256, 0, stream>>>(
            qw, scales, qzeros, Wt, N, K, G / 8);
        const int nbx = N / BN2;
        const int nwg = nbx * (M / BM2);       // 512
        gemm8_kernel<<<nwg, 512, 0, stream>>>(Xb, Wt, bias, out, M, N, K, nbx);
    } else {
        dim3 grid(N / BN, M / BM);
        gemm_fused_kernel<<<grid, 256, 0, stream>>>(
            x, qw, scales, qzeros, bias, out, M, N, K, G);
    }
}

// Round 5
// 499.968 us; speedup vs baseline: 1.0699x; 1.0699x over previous
//
#include <hip/hip_runtime.h>
#include <stdint.h>
#include <stddef.h>

typedef __bf16 bf16;
typedef __bf16 bf16x8 __attribute__((ext_vector_type(8)));
typedef float  f32x4  __attribute__((ext_vector_type(4)));

#define GLOBAL_AS(p) ((const __attribute__((address_space(1))) void*)(p))
#define LDS_AS(p)    ((__attribute__((address_space(3))) void*)(p))

__device__ __forceinline__ void gload_lds16(const bf16* g, bf16* l) {
    // global_load_lds_dwordx4: LDS dest = wave-uniform base + lane*16 (caller guarantees)
    __builtin_amdgcn_global_load_lds(GLOBAL_AS(g), LDS_AS(l), 16, 0, 0);
}

// ---------------------------------------------------------------------------
// x (f32) -> bf16, 8 elems/thread, both directions coalesced
// ---------------------------------------------------------------------------
__global__ __launch_bounds__(256)
void convert_x_kernel(const float* __restrict__ x, bf16* __restrict__ xb, long n8) {
    long t = (long)blockIdx.x * blockDim.x + threadIdx.x;
    if (t >= n8) return;
    const f32x4* p = (const f32x4*)(x + t * 8);
    f32x4 a = p[0], b = p[1];
    bf16x8 v;
#pragma unroll
    for (int j = 0; j < 4; ++j) { v[j] = (bf16)a[j]; v[4 + j] = (bf16)b[j]; }
    *(bf16x8*)(xb + t * 8) = v;
}

// ---------------------------------------------------------------------------
// Dequant to K-TILED layout for BK=64: Wt[K/64][N][64], Wt[t][o][cc] = W^T[o][t*64+cc]
// ---------------------------------------------------------------------------
__global__ __launch_bounds__(256)
void dequant_wt64_kernel(const uint32_t* __restrict__ qw,
                         const float* __restrict__ scales,
                         const float* __restrict__ qzeros,
                         bf16* __restrict__ Wt,
                         int N, int K, int rows_per_group) {
    const int i = blockIdx.x * 256 + threadIdx.x;
    const int w = i >> 6, l = i & 63;
    const int nr8 = K >> 6;                  // 8-row groups (64 k each)
    const int r8 = w % nr8;
    const int o  = (w / nr8) * 8 + (l >> 3);
    const int rr = l & 7;
    const int r  = r8 * 8 + rr;              // qweight row; k = r*8 + j
    if (o >= N) return;
    const uint32_t q = qw[(size_t)r * N + o];
    const int g = r / rows_per_group;
    const float s = scales[(size_t)g * N + o];
    const float z = qzeros[(size_t)g * N + o];
    const float nsz = -s * z;
    bf16x8 v;
#pragma unroll
    for (int j = 0; j < 8; ++j)
        v[j] = (bf16)fmaf((float)((q >> (4 * j)) & 15u), s, nsz);
    *(bf16x8*)(Wt + ((size_t)r8 * N + o) * 64 + rr * 8) = v;
}

// ===========================================================================
// 256x256 8-phase GEMM — SCHEDULE P (fragment-pipelined: reads one phase ahead).
// (Resubmit of R4 source unchanged — R4 bench was an infra failure, same
// signature as R2 which passed on identical resubmit at R3. Full hang audit
// in the comments below re-verified: uniform barriers, satisfiable vmcnt,
// clamped-tail stages, static fragment indices.)
//
// R3 diagnosis: phase wall 1469 cyc = MFMA 621 + LDS-reads 576 + barriers 270.
// Reads and MFMA were SERIAL (reads drained by lgkm before the same phase's
// MFMA, lockstep across waves) -> LDS pipe idle during MFMA and vice versa.
// Fix: phase p issues ds_reads for quantum p+1 into the OTHER fragment set,
// then runs quantum p's MFMA on fragments read last phase; lgkm(0) AFTER the
// MFMA (drain overlaps). One barrier per normal phase; ph4/ph8 add
// vmcnt->barrier before their reads (they read freshly staged tiles).
//
// Quanta (16 MFMA each): Q1=(buf0,kk0,i0-3) Q2=(buf0,kk0,i4-7)
//   Q3=(buf0,kk1,i0-3) Q4=(buf0,kk1,i4-7), Q5-Q8 same on buf1.
// Fragment sets: set0=fa0/fb0 (Q1,Q2,Q5,Q6), set1=fa1/fb1 (Q3,Q4,Q7,Q8).
//
// Per-phase plan (reads feed NEXT phase's quantum; stages per ledger):
//   ph1: MFMA Q1 | read fa0[4:8](buf0,kk0)        | stage B(T+1)->buf1 (4)
//   ph2: MFMA Q2 | read fa1[0:4]+fb1 (buf0,kk1)   |
//   ph3: MFMA Q3 | read fa1[4:8](buf0,kk1)        | stage B(T+2)->buf0 (4)
//   ph4: stage A(T+2)h0->buf0 (2); vmcnt(6); BAR;
//        read fa0[0:4]+fb0 (buf1,kk0) | MFMA Q4
//   ph5: MFMA Q5 | read fa0[4:8](buf1,kk0)        | stage A(T+2)h1->buf0 (2)
//   ph6: MFMA Q6 | read fa1[0:4]+fb1 (buf1,kk1)   |
//   ph7: MFMA Q7 | read fa1[4:8](buf1,kk1)        |
//   ph8: stage A(T+3)->buf1 (4); vmcnt(4); BAR;
//        read fa0[0:4]+fb0 (buf0',kk0) | MFMA Q8
// Every phase: ... sched_barrier; setprio(1) MFMA setprio(0); sched_barrier;
//              lgkm(0); s_barrier; sched_barrier.   (rule #18 fence kept)
//
// vmcnt ledger (loads outstanding; 2 per half-stage):
//   prologue issues 12, vmcnt(4) leaves A(1)=4 = loop entry invariant.
//   entry = 4 (A(T+1), prev ph8). ph1 +4=8, ph3 +4=12, ph4 +2=14
//     -> vmcnt(6) drains A(T+1)+B(T+1): tile T+1 complete before buf1 reads.
//   ph5 +2=8, ph8 +4=12 -> vmcnt(4) drains B(T+2)+A(T+2): buf0 tile T+2
//     complete before buf0' reads; leaves A(T+3)=4 = entry invariant.
// WAR audit (stage after the barrier following the region's LAST read phase;
// reads COMPLETE (lgkm(0)) before every phase's end barrier):
//   B(T+1)->buf1 @ph1 : buf1.B last read prev ph6. OK
//   B(T+2)->buf0 @ph3 : buf0.B last read ph2. OK
//   A(T+2)->buf0 @ph4/5: buf0.A last read ph3. OK
//   A(T+3)->buf1 @ph8 : buf1.A last read ph7. OK
// Register WAR: reads always target the set the current MFMA does NOT use;
//   fa0[4:8] rewritten ph5 after last use Q2(ph2); fb0 rewritten ph8 after
//   Q6(ph6); all static indices (rule #20).
// Tail: clamped tIdx stages (writes land in regions per the same windows);
//   last-iter ph8 reads garbage fragments, never consumed. No divergence,
//   vmcnt always satisfiable; final vmcnt(0) drains dummies.
//
// LDS swizzle (both-sides, rule #21) unchanged (bank conflicts = 0).
// XCD mapping unchanged this round (FETCH attribution isolated).
// ===========================================================================
constexpr int BM2 = 256, BN2 = 256, BK2 = 64;

#define SB()    __builtin_amdgcn_sched_barrier(0)
#define BAR()   __builtin_amdgcn_s_barrier()
#define LGKM0() asm volatile("s_waitcnt lgkmcnt(0)" ::: "memory")
#define VMCNT(N) asm volatile("s_waitcnt vmcnt(" #N ")" ::: "memory")

#define PHASE_TAIL(A, B, IBASE)                          \
    SB();                                                \
    __builtin_amdgcn_s_setprio(1);                       \
    MFMA_HALF(A, B, IBASE);                              \
    __builtin_amdgcn_s_setprio(0);                       \
    SB();                                                \
    LGKM0();                                             \
    BAR();                                               \
    SB()

#define MFMA_HALF(A, B, IBASE)                                             \
    _Pragma("unroll")                                                      \
    for (int i_ = 0; i_ < 4; ++i_) {                                       \
        _Pragma("unroll")                                                  \
        for (int j_ = 0; j_ < 4; ++j_)                                     \
            acc[(IBASE) + i_][j_] = __builtin_amdgcn_mfma_f32_16x16x32_bf16( \
                (A)[(IBASE) + i_], (B)[j_], acc[(IBASE) + i_][j_], 0, 0, 0); \
    }

// 4 A-fragment reads [LO, LO+4) for kk-half KH of buffer BUF (static args)
#define READ_A4(DST, BUF, KH, LO)                                          \
    _Pragma("unroll")                                                      \
    for (int i_ = (LO); i_ < (LO) + 4; ++i_)                               \
        DST[i_] = *(const bf16x8*)(&As[BUF][(wm * 128 + i_ * 16 + lrow) * 64 \
                                           + (((lhi + 4 * (KH)) ^ swz) * 8)]);
#define READ_B4(DST, BUF, KH)                                              \
    _Pragma("unroll")                                                      \
    for (int j_ = 0; j_ < 4; ++j_)                                         \
        DST[j_] = *(const bf16x8*)(&Bs[BUF][(wn * 64 + j_ * 16 + lrow) * 64 \
                                           + (((lhi + 4 * (KH)) ^ swz) * 8)]);

__global__ __launch_bounds__(512, 2)
void gemm8_kernel(const bf16* __restrict__ Ab,   // [M][K] bf16
                  const bf16* __restrict__ Bt,   // [K/64][N][64] bf16 (= W^T k-tiled)
                  const float* __restrict__ bias,
                  float* __restrict__ out,
                  int M, int N, int K, int nbx) {
    __shared__ __align__(16) bf16 As[2][BM2 * BK2];   // 2 x 32KB
    __shared__ __align__(16) bf16 Bs[2][BN2 * BK2];   // 2 x 32KB

    const int tid  = threadIdx.x;
    const int lane = tid & 63;
    const int wave = tid >> 6;
    const int wm = wave >> 2;        // 0..1
    const int wn = wave & 3;         // 0..3

    // T1: bijective XCD swizzle (m204), column-fast (unchanged from R1/R3).
    const int nwg = gridDim.x;
    int wg = blockIdx.x;
    {
        const int q = nwg >> 3, r = nwg & 7;
        const int xcd = wg & 7, off = wg >> 3;
        wg = (xcd < r ? xcd * (q + 1) : r * (q + 1) + (xcd - r) * q) + off;
    }
    const int nby = nwg / nbx;
    const int bx = wg / nby;
    const int by = wg % nby;
    const int m0 = by * BM2;
    const int n0 = bx * BN2;

    const int lrow = lane & 15;
    const int lhi  = lane >> 4;
    const int swz  = (lrow >> 1) & 7;

    const int NT = K >> 6;           // K-tiles
    const int NI = NT >> 1;          // iterations (2 tiles each); K%128==0 guaranteed

    auto stageA = [&](int tIdx, int half, int buf) {
#pragma unroll
        for (int it = 0; it < 2; ++it) {
            const int q  = tid + it * 512;          // chunk in half-tile [0,1024)
            const int rl = q >> 3;                  // row within half
            const int cl = (q & 7) ^ ((rl >> 1) & 7);  // inverse-swizzled source chunk
            gload_lds16(Ab + (size_t)(m0 + half * 128 + rl) * K + tIdx * 64 + cl * 8,
                        &As[buf][half * 8192 + q * 8]);   // linear LDS dest
        }
    };
    auto stageB = [&](int tIdx, int half, int buf) {
#pragma unroll
        for (int it = 0; it < 2; ++it) {
            const int q  = tid + it * 512;
            const int rl = q >> 3;
            const int cl = (q & 7) ^ ((rl >> 1) & 7);
            gload_lds16(Bt + ((size_t)tIdx * N + n0 + half * 128 + rl) * 64 + cl * 8,
                        &Bs[buf][half * 8192 + q * 8]);
        }
    };

    f32x4 acc[8][4];
#pragma unroll
    for (int i = 0; i < 8; ++i)
#pragma unroll
        for (int j = 0; j < 4; ++j) acc[i][j] = (f32x4){0.f, 0.f, 0.f, 0.f};

    // prologue: buf0 tile0 complete + buf1 A-halves in flight; preload set0
    stageA(0, 0, 0); stageA(0, 1, 0); stageB(0, 0, 0); stageB(0, 1, 0);
    stageA(1, 0, 1); stageA(1, 1, 1);
    VMCNT(4);                         // tile0's 8 loads landed; A(1)=4 in flight
    BAR();
    SB();

    bf16x8 fa0[8], fa1[8], fb0[4], fb1[4];
    READ_A4(fa0, 0, 0, 0);
    READ_B4(fb0, 0, 0);
    LGKM0();
    SB();

    for (int i2 = 0; i2 < NI; ++i2) {
        const int t0  = 2 * i2;
        const int tB1 = t0 + 1;                           // buf1 tile (< NT always)
        const int tS2 = (t0 + 2 < NT) ? t0 + 2 : NT - 1;  // clamped dummy at tail
        const int tS3 = (t0 + 3 < NT) ? t0 + 3 : NT - 1;

        // ---- ph1: MFMA Q1 | read fa0[4:8] (buf0,kk0) | stage B(T+1)->buf1
        READ_A4(fa0, 0, 0, 4);
        stageB(tB1, 0, 1);
        stageB(tB1, 1, 1);
        PHASE_TAIL(fa0, fb0, 0);

        // ---- ph2: MFMA Q2 | read set1 lo (buf0,kk1)
        READ_A4(fa1, 0, 1, 0);
        READ_B4(fb1, 0, 1);
        PHASE_TAIL(fa0, fb0, 4);

        // ---- ph3: MFMA Q3 | read fa1[4:8] (buf0,kk1) | stage B(T+2)->buf0
        READ_A4(fa1, 0, 1, 4);
        stageB(tS2, 0, 0);
        stageB(tS2, 1, 0);
        PHASE_TAIL(fa1, fb1, 0);

        // ---- ph4: stage A(T+2)h0->buf0; vmcnt(6); BAR; read set0 (buf1,kk0); MFMA Q4
        stageA(tS2, 0, 0);
        VMCNT(6);
        BAR();
        SB();
        READ_A4(fa0, 1, 0, 0);
        READ_B4(fb0, 1, 0);
        PHASE_TAIL(fa1, fb1, 4);

        // ---- ph5: MFMA Q5 | read fa0[4:8] (buf1,kk0) | stage A(T+2)h1->buf0
        READ_A4(fa0, 1, 0, 4);
        stageA(tS2, 1, 0);
        PHASE_TAIL(fa0, fb0, 0);

        // ---- ph6: MFMA Q6 | read set1 lo (buf1,kk1)
        READ_A4(fa1, 1, 1, 0);
        READ_B4(fb1, 1, 1);
        PHASE_TAIL(fa0, fb0, 4);

        // ---- ph7: MFMA Q7 | read fa1[4:8] (buf1,kk1)
        READ_A4(fa1, 1, 1, 4);
        PHASE_TAIL(fa1, fb1, 0);

        // ---- ph8: stage A(T+3)->buf1; vmcnt(4); BAR; read set0 (buf0',kk0); MFMA Q8
        stageA(tS3, 0, 1);
        stageA(tS3, 1, 1);
        VMCNT(4);
        BAR();
        SB();
        READ_A4(fa0, 0, 0, 0);
        READ_B4(fb0, 0, 0);
        PHASE_TAIL(fa1, fb1, 4);
    }

    asm volatile("s_waitcnt vmcnt(0)" ::: "memory");   // drain before LDS dealloc

    // epilogue: D layout col=lane&15 (n), row=(lane>>4)*4+reg (m); f32 out
#pragma unroll
    for (int j = 0; j < 4; ++j) {
        const int col = n0 + wn * 64 + j * 16 + lrow;
        const float bv = bias[col];
#pragma unroll
        for (int i = 0; i < 8; ++i) {
            const int rbase = m0 + wm * 128 + i * 16 + lhi * 4;
#pragma unroll
            for (int r = 0; r < 4; ++r)
                out[(size_t)(rbase + r) * N + col] = acc[i][j][r] + bv;
        }
    }
}

// ---------------------------------------------------------------------------
// FUSED fallback (small-ws only): f32 x + qweight dequant in-flight.
// 128x128 tile, BK=32, 4 waves (2x2), 4x4 of mfma_f32_16x16x32_bf16.
// ---------------------------------------------------------------------------
constexpr int BM = 128, BN = 128, BK = 32;

__global__ __launch_bounds__(256)
void gemm_fused_kernel(const float* __restrict__ Af,      // [M,K] f32
                       const uint32_t* __restrict__ qw,   // [K/8,N]
                       const float* __restrict__ scales,  // [K/G,N] f32
                       const float* __restrict__ qzeros,  // [K/G,N] f32
                       const float* __restrict__ bias,    // [N] f32
                       float* __restrict__ out,           // [M,N] f32
                       int M, int N, int K, int G) {
    __shared__ __align__(16) bf16 As2[BM * BK];
    __shared__ __align__(16) bf16 Bs2[BN * BK];

    const int tid  = threadIdx.x;
    const int lane = tid & 63;
    const int wave = tid >> 6;
    const int wmm = wave & 1;
    const int wnn = wave >> 1;
    const int m0 = blockIdx.y * BM;
    const int n0 = blockIdx.x * BN;

    const int lr = lane & 15;
    const int lk8 = (lane >> 4) * 8;

    f32x4 acc[4][4];
#pragma unroll
    for (int i = 0; i < 4; ++i)
#pragma unroll
        for (int j = 0; j < 4; ++j) acc[i][j] = (f32x4){0.f, 0.f, 0.f, 0.f};

    for (int kt = 0; kt < K; kt += BK) {
#pragma unroll
        for (int it = 0; it < 2; ++it) {
            const int c = tid + it * 256;
            const int row = c >> 2;
            const int kc  = (c & 3) * 8;
            const f32x4* p = (const f32x4*)(Af + (size_t)(m0 + row) * K + kt + kc);
            f32x4 a = p[0], b = p[1];
            bf16x8 v;
#pragma unroll
            for (int j = 0; j < 4; ++j) { v[j] = (bf16)a[j]; v[4 + j] = (bf16)b[j]; }
            *(bf16x8*)(As2 + row * BK + kc) = v;
        }
        const int g = kt / G;
#pragma unroll
        for (int it = 0; it < 2; ++it) {
            const int idx = tid + it * 256;
            const int rl = idx >> 7;
            const int nl = idx & 127;
            uint32_t q = qw[(size_t)(kt / 8 + rl) * N + n0 + nl];
            float s = scales[(size_t)g * N + n0 + nl];
            float z = qzeros[(size_t)g * N + n0 + nl];
            float nsz = -s * z;
            bf16x8 v;
#pragma unroll
            for (int j = 0; j < 8; ++j)
                v[j] = (bf16)fmaf((float)((q >> (4 * j)) & 15u), s, nsz);
            *(bf16x8*)(Bs2 + nl * BK + rl * 8) = v;
        }
        __syncthreads();

        bf16x8 a[4], b[4];
#pragma unroll
        for (int i = 0; i < 4; ++i)
            a[i] = *(const bf16x8*)(As2 + (wmm * 64 + i * 16 + lr) * BK + lk8);
#pragma unroll
        for (int j = 0; j < 4; ++j)
            b[j] = *(const bf16x8*)(Bs2 + (wnn * 64 + j * 16 + lr) * BK + lk8);

#pragma unroll
        for (int i = 0; i < 4; ++i)
#pragma unroll
            for (int j = 0; j < 4; ++j)
                acc[i][j] = __builtin_amdgcn_mfma_f32_16x16x32_bf16(
                    a[i], b[j], acc[i][j], 0, 0, 0);
        __syncthreads();
    }

#pragma unroll
    for (int j = 0; j < 4; ++j) {
        const int col = n0 + wnn * 64 + j * 16 + (lane & 15);
        const float bv = bias[col];
#pragma unroll
        for (int i = 0; i < 4; ++i) {
            const int rbase = m0 + wmm * 64 + i * 16 + (lane >> 4) * 4;
#pragma unroll
            for (int r = 0; r < 4; ++r)
                out[(size_t)(rbase + r) * N + col] = acc[i][j][r] + bv;
        }
    }
}

extern "C" void kernel_launch(void* const* d_in, const int* in_sizes, int n_in,
                              void* d_out, int out_size, void* d_ws, size_t ws_size,
                              hipStream_t stream) {
    // fp16 reference tensors are stored as FLOAT32 by the harness
    const float*    x      = (const float*)d_in[0];
    const uint32_t* qw     = (const uint32_t*)d_in[1];
    const float*    scales = (const float*)d_in[2];
    const float*    qzeros = (const float*)d_in[3];
    const float*    bias   = (const float*)d_in[4];
    float*          out    = (float*)d_out;

    const int N = in_sizes[4];                 // 4096
    const int K = (in_sizes[1] / N) * 8;       // 4096
    const int M = in_sizes[0] / K;             // 8192
    const int G = K / (in_sizes[2] / N);       // 64

    const size_t xb_bytes = (size_t)M * K * sizeof(bf16);   // 64 MB
    const size_t wt_bytes = (size_t)N * K * sizeof(bf16);   // 32 MB

    const bool shape_ok = (M % BM2 == 0) && (N % BN2 == 0) && (K % 128 == 0) &&
                          (G % 8 == 0);

    if (shape_ok && ws_size >= xb_bytes + wt_bytes) {
        bf16* Xb = (bf16*)d_ws;
        bf16* Wt = (bf16*)((char*)d_ws + xb_bytes);
        const long n8 = (long)M * K / 8;
        convert_x_kernel<<<(int)((n8 + 255) / 256), 256, 0, stream>>>(x, Xb, n8);
        // waves = (K/64) * (N/8); threads = waves*64
        const long dq_threads = ((long)K >> 6) * (N / 8) * 64;
        dequant_wt64_kernel<<<(int)((dq_threads + 255) / 256), 256, 0, stream>>>(
            qw, scales, qzeros, Wt, N, K, G / 8);
        const int nbx = N / BN2;
        const int nwg = nbx * (M / BM2);       // 512
        gemm8_kernel<<<nwg, 512, 0, stream>>>(Xb, Wt, bias, out, M, N, K, nbx);
    } else {
        dim3 grid(N / BN, M / BM);
        gemm_fused_kernel<<<grid, 256, 0, stream>>>(
            x, qw, scales, qzeros, bias, out, M, N, K, G);
    }
}